// Round 1
// baseline (2246.409 us; speedup 1.0000x reference)
//
#include <hip/hip_runtime.h>
#include <cstdint>
#include <cstddef>

// GCN on MI355X. Layout: all f32.
//   x[50000,128], edge_index[2,E] (src=row0, dst=row1), W1[128,128], b1[128],
//   W2[128,64], b2[64]. out[50000,64] = log_softmax(gcn2(relu(gcn1(x))))
// Round 0: correctness-first. Edge aggregation via f32 global atomics.

#define N_FEAT 128

__global__ void k_fill1(float* __restrict__ p, int n) {
  int i = blockIdx.x * blockDim.x + threadIdx.x;
  if (i < n) p[i] = 1.0f;   // self-loop contributes 1 to every degree
}

__global__ void k_count(const int* __restrict__ dst, float* __restrict__ deg, int E) {
  int e = blockIdx.x * blockDim.x + threadIdx.x;
  if (e < E) unsafeAtomicAdd(&deg[dst[e]], 1.0f);
}

__global__ void k_rsqrt(float* __restrict__ p, int n) {
  int i = blockIdx.x * blockDim.x + threadIdx.x;
  if (i < n) p[i] = rsqrtf(p[i]);   // deg >= 1 guaranteed by self-loop init
}

// Y[n,NCOL] = (RELU ? relu(X) : X)[n,128] @ W[128,NCOL]
// 256 threads/block, 8 rows per block staged in LDS, W streamed (L1/L2-cached).
template<int NCOL, bool RELU>
__global__ __launch_bounds__(256) void k_gemm(const float* __restrict__ X,
                                              const float* __restrict__ W,
                                              float* __restrict__ Y, int n) {
  constexpr int RT   = 256 / NCOL;   // threads stacked over rows: 2 (NCOL=128) or 4 (64)
  constexpr int ROWS = 8;
  constexpr int ACC  = ROWS / RT;    // accumulators per thread: 4 or 2
  __shared__ float Xl[ROWS][128];
  int row0 = blockIdx.x * ROWS;
  for (int idx = threadIdx.x; idx < ROWS * 128; idx += 256) {
    int r = idx >> 7, k = idx & 127;
    int row = row0 + r;
    float v = (row < n) ? X[(size_t)row * 128 + k] : 0.0f;
    if (RELU) v = fmaxf(v, 0.0f);
    Xl[r][k] = v;
  }
  __syncthreads();
  int j  = threadIdx.x % NCOL;
  int rs = threadIdx.x / NCOL;
  float acc[ACC];
#pragma unroll
  for (int a = 0; a < ACC; ++a) acc[a] = 0.0f;
#pragma unroll 8
  for (int k = 0; k < 128; ++k) {
    float w = W[k * NCOL + j];      // coalesced, broadcast-reused across RT row-threads
#pragma unroll
    for (int a = 0; a < ACC; ++a) acc[a] += Xl[rs + a * RT][k] * w;
  }
#pragma unroll
  for (int a = 0; a < ACC; ++a) {
    int row = row0 + rs + a * RT;
    if (row < n) Y[(size_t)row * NCOL + j] = acc[a];
  }
}

// AGG[i,j] = bias[j] + XW[i,j] * dinv[i]^2   (self-loop message + bias)
template<int NCOL>
__global__ void k_selfinit(const float* __restrict__ XW, const float* __restrict__ dinv,
                           const float* __restrict__ bias, float* __restrict__ AGG, int n) {
  size_t idx = (size_t)blockIdx.x * blockDim.x + threadIdx.x;
  if (idx >= (size_t)n * NCOL) return;
  int i = (int)(idx / NCOL);
  int j = (int)(idx % NCOL);
  float di = dinv[i];
  AGG[idx] = bias[j] + XW[idx] * di * di;
}

// Per edge: AGG[dst] += XW[src] * dinv[src]*dinv[dst].  NCOL/4 threads per edge.
template<int NCOL>
__global__ void k_edge(const int* __restrict__ src, const int* __restrict__ dst,
                       const float* __restrict__ dinv, const float* __restrict__ XW,
                       float* __restrict__ AGG, int E) {
  constexpr int TPE = NCOL / 4;
  size_t tid = (size_t)blockIdx.x * blockDim.x + threadIdx.x;
  int e = (int)(tid / TPE);
  int c = (int)(tid % TPE) * 4;
  if (e >= E) return;
  int s = src[e], d = dst[e];
  float nrm = dinv[s] * dinv[d];
  float4 v = *(const float4*)(XW + (size_t)s * NCOL + c);
  float* o = AGG + (size_t)d * NCOL + c;
  unsafeAtomicAdd(o + 0, v.x * nrm);
  unsafeAtomicAdd(o + 1, v.y * nrm);
  unsafeAtomicAdd(o + 2, v.z * nrm);
  unsafeAtomicAdd(o + 3, v.w * nrm);
}

// In-place log_softmax over rows of 64. One wave (64 lanes) per row.
__global__ void k_logsoftmax(float* __restrict__ OUT, int n) {
  int gid  = blockIdx.x * blockDim.x + threadIdx.x;
  int row  = gid >> 6;
  int lane = gid & 63;
  if (row >= n) return;
  float v = OUT[(size_t)row * 64 + lane];
  float m = v;
  for (int o = 32; o > 0; o >>= 1) m = fmaxf(m, __shfl_xor(m, o));
  float ex = expf(v - m);
  float s = ex;
  for (int o = 32; o > 0; o >>= 1) s += __shfl_xor(s, o);
  OUT[(size_t)row * 64 + lane] = v - m - logf(s);
}

extern "C" void kernel_launch(void* const* d_in, const int* in_sizes, int n_in,
                              void* d_out, int out_size, void* d_ws, size_t ws_size,
                              hipStream_t stream) {
  const float* x  = (const float*)d_in[0];
  const int*   ei = (const int*)d_in[1];
  const float* W1 = (const float*)d_in[2];
  const float* b1 = (const float*)d_in[3];
  const float* W2 = (const float*)d_in[4];
  const float* b2 = (const float*)d_in[5];
  float* out = (float*)d_out;

  const int n = in_sizes[0] / N_FEAT;   // 50000
  const int E = in_sizes[1] / 2;        // 800000
  const int* src = ei;
  const int* dst = ei + E;

  // Workspace carve-up (~51.5 MB): dinv | xw[n,128] | h[n,128]; hw overlays xw.
  char* ws = (char*)d_ws;
  size_t off = 0;
  float* dinv = (float*)(ws + off); off += (((size_t)n * 4) + 255) & ~(size_t)255;
  float* xw   = (float*)(ws + off); off += (((size_t)n * 128 * 4) + 255) & ~(size_t)255;
  float* h    = (float*)(ws + off);
  float* hw   = xw;  // xw dead after layer-1 aggregation

  // Degrees -> dinv
  k_fill1<<<(n + 255) / 256, 256, 0, stream>>>(dinv, n);
  k_count<<<(E + 255) / 256, 256, 0, stream>>>(dst, dinv, E);
  k_rsqrt<<<(n + 255) / 256, 256, 0, stream>>>(dinv, n);

  // Layer 1
  k_gemm<128, false><<<(n + 7) / 8, 256, 0, stream>>>(x, W1, xw, n);
  k_selfinit<128><<<(int)(((size_t)n * 128 + 255) / 256), 256, 0, stream>>>(xw, dinv, b1, h, n);
  k_edge<128><<<(int)(((size_t)E * 32 + 255) / 256), 256, 0, stream>>>(src, dst, dinv, xw, h, E);

  // Layer 2 (ReLU fused into GEMM2's row load)
  k_gemm<64, true><<<(n + 7) / 8, 256, 0, stream>>>(h, W2, hw, n);
  k_selfinit<64><<<(int)(((size_t)n * 64 + 255) / 256), 256, 0, stream>>>(hw, dinv, b2, out, n);
  k_edge<64><<<(int)(((size_t)E * 16 + 255) / 256), 256, 0, stream>>>(src, dst, dinv, hw, out, E);

  // log_softmax in place on d_out
  k_logsoftmax<<<(int)(((size_t)n * 64 + 255) / 256), 256, 0, stream>>>(out, n);
}

// Round 2
// 470.038 us; speedup vs baseline: 4.7792x; 4.7792x over previous
//
#include <hip/hip_runtime.h>
#include <cstdint>
#include <cstddef>

// GCN on MI355X, round 2: CSR-gather aggregation (no f32 atomics).
//   x[50000,128], edge_index[2,E], W1[128,128], b1[128], W2[128,64], b2[64]
//   out[50000,64] = log_softmax(gcn2(relu(gcn1(x))))
// Pipeline: hist(dst) -> scan(rowptr,dinv) -> fill CSR(src,norm) ->
//   GEMM1 -> agg128(+bias+selfloop+ReLU) -> GEMM2 -> agg64(+bias+log_softmax)

#define N_FEAT 128

__global__ void k_hist(const int* __restrict__ dst, int* __restrict__ cnt, int E) {
  int e = blockIdx.x * blockDim.x + threadIdx.x;
  if (e < E) atomicAdd(&cnt[dst[e]], 1);
}

// Single-block exclusive scan of cnt[n] -> rowptr[n+1]; also cursor=rowptr and
// dinv[i] = rsqrt(deg_in + 1 self-loop).
__global__ __launch_bounds__(1024) void k_scan(const int* __restrict__ cnt,
                                               int* __restrict__ rowptr,
                                               int* __restrict__ cursor,
                                               float* __restrict__ dinv,
                                               int n, int E) {
  __shared__ int lds[1024];
  int t = threadIdx.x;
  int chunk = (n + 1023) / 1024;
  int lo = t * chunk, hi = min(lo + chunk, n);
  int s = 0;
  for (int i = lo; i < hi; ++i) s += cnt[i];
  lds[t] = s;
  __syncthreads();
  for (int off = 1; off < 1024; off <<= 1) {   // Hillis-Steele inclusive scan
    int v = (t >= off) ? lds[t - off] : 0;
    __syncthreads();
    lds[t] += v;
    __syncthreads();
  }
  int run = lds[t] - s;                        // exclusive base for this chunk
  for (int i = lo; i < hi; ++i) {
    rowptr[i] = run;
    cursor[i] = run;
    dinv[i] = rsqrtf((float)(cnt[i] + 1));
    run += cnt[i];
  }
  if (t == 0) rowptr[n] = E;
}

// Place each edge at its CSR slot; pack (src, dinv[src]*dinv[dst]) as int2.
__global__ void k_fill(const int* __restrict__ src, const int* __restrict__ dst,
                       const float* __restrict__ dinv, int* __restrict__ cursor,
                       int2* __restrict__ csr, int E) {
  int e = blockIdx.x * blockDim.x + threadIdx.x;
  if (e >= E) return;
  int s = src[e], d = dst[e];
  int p = atomicAdd(&cursor[d], 1);
  float nrm = dinv[s] * dinv[d];
  csr[p] = make_int2(s, __float_as_int(nrm));
}

// Y[n,NCOL] = X[n,128] @ W[128,NCOL]; 8 rows/block staged in LDS.
template<int NCOL>
__global__ __launch_bounds__(256) void k_gemm(const float* __restrict__ X,
                                              const float* __restrict__ W,
                                              float* __restrict__ Y, int n) {
  constexpr int RT   = 256 / NCOL;
  constexpr int ROWS = 8;
  constexpr int ACC  = ROWS / RT;
  __shared__ float Xl[ROWS][128];
  int row0 = blockIdx.x * ROWS;
  for (int idx = threadIdx.x; idx < ROWS * 128; idx += 256) {
    int r = idx >> 7, k = idx & 127;
    int row = row0 + r;
    Xl[r][k] = (row < n) ? X[(size_t)row * 128 + k] : 0.0f;
  }
  __syncthreads();
  int j  = threadIdx.x % NCOL;
  int rs = threadIdx.x / NCOL;
  float acc[ACC];
#pragma unroll
  for (int a = 0; a < ACC; ++a) acc[a] = 0.0f;
#pragma unroll 8
  for (int k = 0; k < 128; ++k) {
    float w = W[k * NCOL + j];
#pragma unroll
    for (int a = 0; a < ACC; ++a) acc[a] += Xl[rs + a * RT][k] * w;
  }
#pragma unroll
  for (int a = 0; a < ACC; ++a) {
    int row = row0 + rs + a * RT;
    if (row < n) Y[(size_t)row * NCOL + j] = acc[a];
  }
}

// Layer-1 aggregation: h[i,:] = relu(b1 + dinv[i]^2*xw[i,:] + sum_e nrm_e*xw[src_e,:])
// One wave per node; lane owns 2 cols (float2). 2-deep unroll for load ILP.
__global__ __launch_bounds__(256) void k_agg128(const int2* __restrict__ csr,
                                                const int* __restrict__ rowptr,
                                                const float* __restrict__ dinv,
                                                const float* __restrict__ bias,
                                                const float* __restrict__ xw,
                                                float* __restrict__ h, int n) {
  int wid  = (blockIdx.x * blockDim.x + threadIdx.x) >> 6;
  int lane = threadIdx.x & 63;
  if (wid >= n) return;
  const float2* xw2 = (const float2*)xw;
  int beg = rowptr[wid], end = rowptr[wid + 1];
  float di = dinv[wid];
  float sl = di * di;
  float2 v = xw2[(size_t)wid * 64 + lane];
  float2 acc0 = { bias[2 * lane] + v.x * sl, bias[2 * lane + 1] + v.y * sl };
  float2 acc1 = { 0.0f, 0.0f };
  int j = beg;
  for (; j + 1 < end; j += 2) {
    int2 p0 = csr[j], p1 = csr[j + 1];
    float2 r0 = xw2[(size_t)p0.x * 64 + lane];
    float2 r1 = xw2[(size_t)p1.x * 64 + lane];
    float n0 = __int_as_float(p0.y), n1 = __int_as_float(p1.y);
    acc0.x += r0.x * n0; acc0.y += r0.y * n0;
    acc1.x += r1.x * n1; acc1.y += r1.y * n1;
  }
  if (j < end) {
    int2 p0 = csr[j];
    float2 r0 = xw2[(size_t)p0.x * 64 + lane];
    float n0 = __int_as_float(p0.y);
    acc0.x += r0.x * n0; acc0.y += r0.y * n0;
  }
  float2 o = { fmaxf(acc0.x + acc1.x, 0.0f), fmaxf(acc0.y + acc1.y, 0.0f) };
  ((float2*)h)[(size_t)wid * 64 + lane] = o;
}

// Layer-2 aggregation + fused log_softmax. One wave per node; lane owns 1 col.
__global__ __launch_bounds__(256) void k_agg64ls(const int2* __restrict__ csr,
                                                 const int* __restrict__ rowptr,
                                                 const float* __restrict__ dinv,
                                                 const float* __restrict__ bias,
                                                 const float* __restrict__ hw,
                                                 float* __restrict__ out, int n) {
  int wid  = (blockIdx.x * blockDim.x + threadIdx.x) >> 6;
  int lane = threadIdx.x & 63;
  if (wid >= n) return;
  int beg = rowptr[wid], end = rowptr[wid + 1];
  float di = dinv[wid];
  float acc0 = bias[lane] + hw[(size_t)wid * 64 + lane] * di * di;
  float acc1 = 0.0f;
  int j = beg;
  for (; j + 1 < end; j += 2) {
    int2 p0 = csr[j], p1 = csr[j + 1];
    acc0 += hw[(size_t)p0.x * 64 + lane] * __int_as_float(p0.y);
    acc1 += hw[(size_t)p1.x * 64 + lane] * __int_as_float(p1.y);
  }
  if (j < end) {
    int2 p = csr[j];
    acc0 += hw[(size_t)p.x * 64 + lane] * __int_as_float(p.y);
  }
  float v = acc0 + acc1;
  float m = v;
  for (int o = 32; o > 0; o >>= 1) m = fmaxf(m, __shfl_xor(m, o));
  float ex = expf(v - m);
  float s = ex;
  for (int o = 32; o > 0; o >>= 1) s += __shfl_xor(s, o);
  out[(size_t)wid * 64 + lane] = v - m - logf(s);
}

extern "C" void kernel_launch(void* const* d_in, const int* in_sizes, int n_in,
                              void* d_out, int out_size, void* d_ws, size_t ws_size,
                              hipStream_t stream) {
  const float* x  = (const float*)d_in[0];
  const int*   ei = (const int*)d_in[1];
  const float* W1 = (const float*)d_in[2];
  const float* b1 = (const float*)d_in[3];
  const float* W2 = (const float*)d_in[4];
  const float* b2 = (const float*)d_in[5];
  float* out = (float*)d_out;

  const int n = in_sizes[0] / N_FEAT;   // 50000
  const int E = in_sizes[1] / 2;        // 800000
  const int* src = ei;
  const int* dst = ei + E;

  auto align = [](size_t v) { return (v + 255) & ~(size_t)255; };
  char* ws = (char*)d_ws;
  size_t off = 0;
  int*   cnt    = (int*)  (ws + off); off += align((size_t)n * 4);
  int*   rowptr = (int*)  (ws + off); off += align((size_t)(n + 1) * 4);
  int*   cursor = (int*)  (ws + off); off += align((size_t)n * 4);
  float* dinv   = (float*)(ws + off); off += align((size_t)n * 4);
  int2*  csr    = (int2*) (ws + off); off += align((size_t)E * 8);
  float* xw     = (float*)(ws + off); off += align((size_t)n * 128 * 4);
  float* h      = (float*)(ws + off); off += align((size_t)n * 128 * 4);
  float* hw     = xw;  // xw dead after layer-1 aggregation

  hipMemsetAsync(cnt, 0, (size_t)n * 4, stream);
  k_hist<<<(E + 255) / 256, 256, 0, stream>>>(dst, cnt, E);
  k_scan<<<1, 1024, 0, stream>>>(cnt, rowptr, cursor, dinv, n, E);
  k_fill<<<(E + 255) / 256, 256, 0, stream>>>(src, dst, dinv, cursor, csr, E);

  // Layer 1
  k_gemm<128><<<(n + 7) / 8, 256, 0, stream>>>(x, W1, xw, n);
  k_agg128<<<(int)(((size_t)n * 64 + 255) / 256), 256, 0, stream>>>(
      csr, rowptr, dinv, b1, xw, h, n);

  // Layer 2 (h already ReLU'd)
  k_gemm<64><<<(n + 7) / 8, 256, 0, stream>>>(h, W2, hw, n);
  k_agg64ls<<<(int)(((size_t)n * 64 + 255) / 256), 256, 0, stream>>>(
      csr, rowptr, dinv, b2, hw, out, n);
}

// Round 3
// 341.547 us; speedup vs baseline: 6.5772x; 1.3762x over previous
//
#include <hip/hip_runtime.h>
#include <cstdint>
#include <cstddef>

// GCN on MI355X, round 3: parallel scan + bf16 gather tables.
//   out[50000,64] = log_softmax(gcn2(relu(gcn1(x))))
// Pipeline: hist(dst) -> 2-level scan -> fill CSR(src,norm) ->
//   GEMM1(f32->bf16) -> agg128(bf16 gather, f32 acc, bf16 out) ->
//   GEMM2(bf16 in, f32 out) -> agg64(f32 gather)+log_softmax

#define N_FEAT 128

__device__ __forceinline__ unsigned f2bf(float f) {
  unsigned u = __float_as_uint(f);
  return (u + 0x7FFFu + ((u >> 16) & 1u)) >> 16;   // round-to-nearest-even
}

__global__ void k_hist(const int* __restrict__ dst, int* __restrict__ cnt, int E) {
  int e = blockIdx.x * blockDim.x + threadIdx.x;
  if (e < E) atomicAdd(&cnt[dst[e]], 1);
}

// Two-level scan: per-block sums -> scan block sums -> per-block local scan.
__global__ __launch_bounds__(256) void k_bsum(const int* __restrict__ cnt,
                                              int* __restrict__ bsum, int n) {
  int i = blockIdx.x * 256 + threadIdx.x;
  int v = (i < n) ? cnt[i] : 0;
  for (int o = 32; o > 0; o >>= 1) v += __shfl_down(v, o);
  __shared__ int w[4];
  if ((threadIdx.x & 63) == 0) w[threadIdx.x >> 6] = v;
  __syncthreads();
  if (threadIdx.x == 0) bsum[blockIdx.x] = w[0] + w[1] + w[2] + w[3];
}

__global__ __launch_bounds__(256) void k_bscan(const int* __restrict__ bsum,
                                               int* __restrict__ bbase, int nb) {
  __shared__ int lds[256];
  int t = threadIdx.x;
  int v = (t < nb) ? bsum[t] : 0;
  lds[t] = v;
  __syncthreads();
  for (int o = 1; o < 256; o <<= 1) {
    int u = (t >= o) ? lds[t - o] : 0;
    __syncthreads();
    lds[t] += u;
    __syncthreads();
  }
  if (t < nb) bbase[t] = lds[t] - v;   // exclusive
}

__global__ __launch_bounds__(256) void k_scan2(const int* __restrict__ cnt,
                                               const int* __restrict__ bbase,
                                               int* __restrict__ rowptr,
                                               int* __restrict__ cursor,
                                               float* __restrict__ dinv,
                                               int n, int E) {
  __shared__ int lds[256];
  int t = threadIdx.x;
  int i = blockIdx.x * 256 + t;
  int c = (i < n) ? cnt[i] : 0;
  lds[t] = c;
  __syncthreads();
  for (int o = 1; o < 256; o <<= 1) {
    int u = (t >= o) ? lds[t - o] : 0;
    __syncthreads();
    lds[t] += u;
    __syncthreads();
  }
  if (i < n) {
    int excl = bbase[blockIdx.x] + lds[t] - c;
    rowptr[i] = excl;
    cursor[i] = excl;
    dinv[i] = rsqrtf((float)(c + 1));   // +1 self-loop
    if (i == n - 1) rowptr[n] = E;
  }
}

__global__ void k_fill(const int* __restrict__ src, const int* __restrict__ dst,
                       const float* __restrict__ dinv, int* __restrict__ cursor,
                       int2* __restrict__ csr, int E) {
  int e = blockIdx.x * blockDim.x + threadIdx.x;
  if (e >= E) return;
  int s = src[e], d = dst[e];
  int p = atomicAdd(&cursor[d], 1);
  float nrm = dinv[s] * dinv[d];
  csr[p] = make_int2(s, __float_as_int(nrm));
}

// GEMM1: xwb[n,128](bf16) = X[n,128](f32) @ W1[128,128]
__global__ __launch_bounds__(256) void k_gemm1(const float* __restrict__ X,
                                               const float* __restrict__ W,
                                               unsigned short* __restrict__ Yb, int n) {
  constexpr int ROWS = 8;
  __shared__ float Xl[ROWS][128];
  int row0 = blockIdx.x * ROWS;
  for (int idx = threadIdx.x; idx < ROWS * 128; idx += 256) {
    int r = idx >> 7, k = idx & 127;
    int row = row0 + r;
    Xl[r][k] = (row < n) ? X[(size_t)row * 128 + k] : 0.0f;
  }
  __syncthreads();
  int j  = threadIdx.x & 127;
  int rs = threadIdx.x >> 7;       // 0..1
  float acc[4];
#pragma unroll
  for (int a = 0; a < 4; ++a) acc[a] = 0.0f;
#pragma unroll 8
  for (int k = 0; k < 128; ++k) {
    float w = W[k * 128 + j];
#pragma unroll
    for (int a = 0; a < 4; ++a) acc[a] += Xl[rs + a * 2][k] * w;
  }
#pragma unroll
  for (int a = 0; a < 4; ++a) {
    int row = row0 + rs + a * 2;
    if (row < n) Yb[(size_t)row * 128 + j] = (unsigned short)f2bf(acc[a]);
  }
}

// GEMM2: hw[n,64](f32) = Hb[n,128](bf16) @ W2[128,64]
__global__ __launch_bounds__(256) void k_gemm2(const unsigned short* __restrict__ Hb,
                                               const float* __restrict__ W,
                                               float* __restrict__ Y, int n) {
  constexpr int ROWS = 8;
  __shared__ float Xl[ROWS][128];
  int row0 = blockIdx.x * ROWS;
  const unsigned* Hu = (const unsigned*)Hb;
  for (int idx = threadIdx.x; idx < ROWS * 64; idx += 256) {
    int r = idx >> 6, k2 = idx & 63;
    int row = row0 + r;
    unsigned u = (row < n) ? Hu[(size_t)row * 64 + k2] : 0u;
    Xl[r][2 * k2]     = __uint_as_float(u << 16);
    Xl[r][2 * k2 + 1] = __uint_as_float(u & 0xFFFF0000u);
  }
  __syncthreads();
  int j  = threadIdx.x & 63;
  int rs = threadIdx.x >> 6;       // 0..3
  float acc[2];
  acc[0] = acc[1] = 0.0f;
#pragma unroll 8
  for (int k = 0; k < 128; ++k) {
    float w = W[k * 64 + j];
#pragma unroll
    for (int a = 0; a < 2; ++a) acc[a] += Xl[rs + a * 4][k] * w;
  }
#pragma unroll
  for (int a = 0; a < 2; ++a) {
    int row = row0 + rs + a * 4;
    if (row < n) Y[(size_t)row * 64 + j] = acc[a];
  }
}

// Layer-1 aggregation, bf16 table: hb[i,:] = relu(b1 + dinv^2*xwb[i,:] + sum nrm*xwb[src,:])
// One wave/node; lane owns cols {2l, 2l+1} packed in one uint.
__global__ __launch_bounds__(256) void k_agg128(const int2* __restrict__ csr,
                                                const int* __restrict__ rowptr,
                                                const float* __restrict__ dinv,
                                                const float* __restrict__ bias,
                                                const unsigned* __restrict__ xwb,
                                                unsigned* __restrict__ hb, int n) {
  int wid  = (blockIdx.x * blockDim.x + threadIdx.x) >> 6;
  int lane = threadIdx.x & 63;
  if (wid >= n) return;
  int beg = rowptr[wid], end = rowptr[wid + 1];
  float di = dinv[wid];
  float sl = di * di;
  unsigned us = xwb[(size_t)wid * 64 + lane];
  float ax = bias[2 * lane]     + __uint_as_float(us << 16) * sl;
  float ay = bias[2 * lane + 1] + __uint_as_float(us & 0xFFFF0000u) * sl;
  float bx = 0.0f, by = 0.0f;
  int j = beg;
  for (; j + 1 < end; j += 2) {
    int2 p0 = csr[j], p1 = csr[j + 1];
    unsigned u0 = xwb[(size_t)p0.x * 64 + lane];
    unsigned u1 = xwb[(size_t)p1.x * 64 + lane];
    float n0 = __int_as_float(p0.y), n1 = __int_as_float(p1.y);
    ax += __uint_as_float(u0 << 16) * n0;
    ay += __uint_as_float(u0 & 0xFFFF0000u) * n0;
    bx += __uint_as_float(u1 << 16) * n1;
    by += __uint_as_float(u1 & 0xFFFF0000u) * n1;
  }
  if (j < end) {
    int2 p0 = csr[j];
    unsigned u0 = xwb[(size_t)p0.x * 64 + lane];
    float n0 = __int_as_float(p0.y);
    ax += __uint_as_float(u0 << 16) * n0;
    ay += __uint_as_float(u0 & 0xFFFF0000u) * n0;
  }
  float ox = fmaxf(ax + bx, 0.0f), oy = fmaxf(ay + by, 0.0f);
  hb[(size_t)wid * 64 + lane] = f2bf(ox) | (f2bf(oy) << 16);
}

// Layer-2 aggregation (f32 table) + fused log_softmax. One wave/node, lane=col.
__global__ __launch_bounds__(256) void k_agg64ls(const int2* __restrict__ csr,
                                                 const int* __restrict__ rowptr,
                                                 const float* __restrict__ dinv,
                                                 const float* __restrict__ bias,
                                                 const float* __restrict__ hw,
                                                 float* __restrict__ out, int n) {
  int wid  = (blockIdx.x * blockDim.x + threadIdx.x) >> 6;
  int lane = threadIdx.x & 63;
  if (wid >= n) return;
  int beg = rowptr[wid], end = rowptr[wid + 1];
  float di = dinv[wid];
  float acc0 = bias[lane] + hw[(size_t)wid * 64 + lane] * di * di;
  float acc1 = 0.0f;
  int j = beg;
  for (; j + 1 < end; j += 2) {
    int2 p0 = csr[j], p1 = csr[j + 1];
    acc0 += hw[(size_t)p0.x * 64 + lane] * __int_as_float(p0.y);
    acc1 += hw[(size_t)p1.x * 64 + lane] * __int_as_float(p1.y);
  }
  if (j < end) {
    int2 p = csr[j];
    acc0 += hw[(size_t)p.x * 64 + lane] * __int_as_float(p.y);
  }
  float v = acc0 + acc1;
  float m = v;
  for (int o = 32; o > 0; o >>= 1) m = fmaxf(m, __shfl_xor(m, o));
  float ex = expf(v - m);
  float s = ex;
  for (int o = 32; o > 0; o >>= 1) s += __shfl_xor(s, o);
  out[(size_t)wid * 64 + lane] = v - m - logf(s);
}

extern "C" void kernel_launch(void* const* d_in, const int* in_sizes, int n_in,
                              void* d_out, int out_size, void* d_ws, size_t ws_size,
                              hipStream_t stream) {
  const float* x  = (const float*)d_in[0];
  const int*   ei = (const int*)d_in[1];
  const float* W1 = (const float*)d_in[2];
  const float* b1 = (const float*)d_in[3];
  const float* W2 = (const float*)d_in[4];
  const float* b2 = (const float*)d_in[5];
  float* out = (float*)d_out;

  const int n = in_sizes[0] / N_FEAT;   // 50000
  const int E = in_sizes[1] / 2;        // 800000
  const int* src = ei;
  const int* dst = ei + E;
  const int nb = (n + 255) / 256;       // 196 scan blocks

  auto align = [](size_t v) { return (v + 255) & ~(size_t)255; };
  char* ws = (char*)d_ws;
  size_t off = 0;
  int*      cnt    = (int*)     (ws + off); off += align((size_t)n * 4);
  int*      rowptr = (int*)     (ws + off); off += align((size_t)(n + 1) * 4);
  int*      cursor = (int*)     (ws + off); off += align((size_t)n * 4);
  float*    dinv   = (float*)   (ws + off); off += align((size_t)n * 4);
  int*      bsum   = (int*)     (ws + off); off += align(256 * 4);
  int*      bbase  = (int*)     (ws + off); off += align(256 * 4);
  int2*     csr    = (int2*)    (ws + off); off += align((size_t)E * 8);
  unsigned* xwb    = (unsigned*)(ws + off); off += align((size_t)n * 64 * 4);  // bf16[n,128]
  unsigned* hb     = (unsigned*)(ws + off); off += align((size_t)n * 64 * 4);  // bf16[n,128]
  float*    hw     = (float*)xwb;  // f32[n,64] overlays xwb (dead after agg128)

  hipMemsetAsync(cnt, 0, (size_t)n * 4, stream);
  k_hist<<<(E + 255) / 256, 256, 0, stream>>>(dst, cnt, E);
  k_bsum<<<nb, 256, 0, stream>>>(cnt, bsum, n);
  k_bscan<<<1, 256, 0, stream>>>(bsum, bbase, nb);
  k_scan2<<<nb, 256, 0, stream>>>(cnt, bbase, rowptr, cursor, dinv, n, E);
  k_fill<<<(E + 255) / 256, 256, 0, stream>>>(src, dst, dinv, cursor, csr, E);

  // Layer 1
  k_gemm1<<<(n + 7) / 8, 256, 0, stream>>>(x, W1, (unsigned short*)xwb, n);
  k_agg128<<<(int)(((size_t)n * 64 + 255) / 256), 256, 0, stream>>>(
      csr, rowptr, dinv, b1, xwb, hb, n);

  // Layer 2
  k_gemm2<<<(n + 7) / 8, 256, 0, stream>>>((const unsigned short*)hb, W2, hw, n);
  k_agg64ls<<<(int)(((size_t)n * 64 + 255) / 256), 256, 0, stream>>>(
      csr, rowptr, dinv, b2, hw, out, n);
}

// Round 4
// 279.814 us; speedup vs baseline: 8.0282x; 1.2206x over previous
//
#include <hip/hip_runtime.h>
#include <cstdint>
#include <cstddef>

// GCN on MI355X, round 4.
//   out[50000,64] = log_softmax(gcn2(relu(gcn1(x))))
// Pipeline: hist(+rank) -> 2-level padded scan -> pad -> fill (atomic-free) ->
//   GEMM1(f32->bf16, b128-broadcast) -> agg128(4-wide ILP) ->
//   GEMM2(bf16->bf16) -> agg64(half-wave, bf16 gathers)+log_softmax
// CSR rows padded to multiples of 4 edges (src=0, nrm=0 dummies) so the
// aggregation loops use aligned int4/float4 descriptor loads, no guards.

#define N_FEAT 128

__device__ __forceinline__ unsigned f2bf(float f) {
  unsigned u = __float_as_uint(f);
  return (u + 0x7FFFu + ((u >> 16) & 1u)) >> 16;   // round-to-nearest-even
}
__device__ __forceinline__ float bflo(unsigned u) { return __uint_as_float(u << 16); }
__device__ __forceinline__ float bfhi(unsigned u) { return __uint_as_float(u & 0xFFFF0000u); }

// Histogram of dst + per-edge within-row rank (makes fill atomic-free).
__global__ void k_hist(const int* __restrict__ dst, int* __restrict__ cnt,
                       int* __restrict__ rank, int E) {
  int e = blockIdx.x * blockDim.x + threadIdx.x;
  if (e < E) rank[e] = atomicAdd(&cnt[dst[e]], 1);
}

// Per-block sums of PADDED counts (pad each row to multiple of 4).
__global__ __launch_bounds__(256) void k_bsum(const int* __restrict__ cnt,
                                              int* __restrict__ bsum, int n) {
  int i = blockIdx.x * 256 + threadIdx.x;
  int v = (i < n) ? ((cnt[i] + 3) & ~3) : 0;
  for (int o = 32; o > 0; o >>= 1) v += __shfl_down(v, o);
  __shared__ int w[4];
  if ((threadIdx.x & 63) == 0) w[threadIdx.x >> 6] = v;
  __syncthreads();
  if (threadIdx.x == 0) bsum[blockIdx.x] = w[0] + w[1] + w[2] + w[3];
}

__global__ __launch_bounds__(256) void k_bscan(const int* __restrict__ bsum,
                                               int* __restrict__ bbase, int nb) {
  __shared__ int lds[256];
  int t = threadIdx.x;
  int v = (t < nb) ? bsum[t] : 0;
  lds[t] = v;
  __syncthreads();
  for (int o = 1; o < 256; o <<= 1) {
    int u = (t >= o) ? lds[t - o] : 0;
    __syncthreads();
    lds[t] += u;
    __syncthreads();
  }
  if (t < nb) bbase[t] = lds[t] - v;   // exclusive
}

__global__ __launch_bounds__(256) void k_scan2(const int* __restrict__ cnt,
                                               const int* __restrict__ bbase,
                                               int* __restrict__ rowptr,
                                               float* __restrict__ dinv, int n) {
  __shared__ int lds[256];
  int t = threadIdx.x;
  int i = blockIdx.x * 256 + t;
  int c  = (i < n) ? cnt[i] : 0;
  int pc = (c + 3) & ~3;
  lds[t] = pc;
  __syncthreads();
  for (int o = 1; o < 256; o <<= 1) {
    int u = (t >= o) ? lds[t - o] : 0;
    __syncthreads();
    lds[t] += u;
    __syncthreads();
  }
  if (i < n) {
    rowptr[i] = bbase[blockIdx.x] + lds[t] - pc;
    dinv[i] = rsqrtf((float)(c + 1));   // +1 self-loop
  }
}

// Zero the dummy pad slots (<=3 per row).
__global__ void k_pad(const int* __restrict__ rowptr, const int* __restrict__ cnt,
                      int* __restrict__ csrc, float* __restrict__ cnrm, int n) {
  int i = blockIdx.x * blockDim.x + threadIdx.x;
  if (i >= n) return;
  int b = rowptr[i] + cnt[i];
  int e = rowptr[i] + ((cnt[i] + 3) & ~3);
  for (int p = b; p < e; ++p) { csrc[p] = 0; cnrm[p] = 0.0f; }
}

// Atomic-free CSR fill using precomputed ranks.
__global__ void k_fill(const int* __restrict__ src, const int* __restrict__ dst,
                       const int* __restrict__ rank, const int* __restrict__ rowptr,
                       const float* __restrict__ dinv,
                       int* __restrict__ csrc, float* __restrict__ cnrm, int E) {
  int e = blockIdx.x * blockDim.x + threadIdx.x;
  if (e >= E) return;
  int s = src[e], d = dst[e];
  int p = rowptr[d] + rank[e];
  csrc[p] = s;
  cnrm[p] = dinv[s] * dinv[d];
}

// GEMM1: Yb[n,128](bf16) = X[n,128](f32) @ W[128,128].
// 16 rows/block staged TRANSPOSED in LDS; inner loop reads 2 float4 broadcasts.
__global__ __launch_bounds__(256) void k_gemm1(const float* __restrict__ X,
                                               const float* __restrict__ W,
                                               unsigned short* __restrict__ Yb, int n) {
  __shared__ float XlT[128][20];   // [k][row], pad 20 keeps b128 alignment
  int row0 = blockIdx.x * 16;
  for (int it = 0; it < 8; ++it) {
    int idx = threadIdx.x + it * 256;
    int r = idx >> 7, k = idx & 127;
    int row = row0 + r;
    XlT[k][r] = (row < n) ? X[(size_t)row * 128 + k] : 0.0f;
  }
  __syncthreads();
  int j  = threadIdx.x & 127;
  int rs = (threadIdx.x >> 7) * 8;     // rows rs..rs+7
  float acc[8];
#pragma unroll
  for (int a = 0; a < 8; ++a) acc[a] = 0.0f;
#pragma unroll 4
  for (int k = 0; k < 128; ++k) {
    float w = W[k * 128 + j];
    float4 a0 = *(const float4*)&XlT[k][rs];
    float4 a1 = *(const float4*)&XlT[k][rs + 4];
    acc[0] += a0.x * w; acc[1] += a0.y * w; acc[2] += a0.z * w; acc[3] += a0.w * w;
    acc[4] += a1.x * w; acc[5] += a1.y * w; acc[6] += a1.z * w; acc[7] += a1.w * w;
  }
#pragma unroll
  for (int a = 0; a < 8; ++a) {
    int row = row0 + rs + a;
    if (row < n) Yb[(size_t)row * 128 + j] = (unsigned short)f2bf(acc[a]);
  }
}

// GEMM2: hwb[n,64](bf16) = Hb[n,128](bf16) @ W2[128,64].
__global__ __launch_bounds__(256) void k_gemm2(const unsigned* __restrict__ Hu,
                                               const float* __restrict__ W,
                                               unsigned short* __restrict__ Yb, int n) {
  __shared__ float XlT[128][20];
  int row0 = blockIdx.x * 16;
  for (int it = 0; it < 4; ++it) {
    int idx = threadIdx.x + it * 256;
    int r = idx >> 6, k2 = idx & 63;
    int row = row0 + r;
    unsigned u = (row < n) ? Hu[(size_t)row * 64 + k2] : 0u;
    XlT[2 * k2][r]     = bflo(u);
    XlT[2 * k2 + 1][r] = bfhi(u);
  }
  __syncthreads();
  int j  = threadIdx.x & 63;
  int rs = (threadIdx.x >> 6) * 4;     // rows rs..rs+3
  float acc[4];
#pragma unroll
  for (int a = 0; a < 4; ++a) acc[a] = 0.0f;
#pragma unroll 4
  for (int k = 0; k < 128; ++k) {
    float w = W[k * 64 + j];
    float4 a0 = *(const float4*)&XlT[k][rs];
    acc[0] += a0.x * w; acc[1] += a0.y * w; acc[2] += a0.z * w; acc[3] += a0.w * w;
  }
#pragma unroll
  for (int a = 0; a < 4; ++a) {
    int row = row0 + rs + a;
    if (row < n) Yb[(size_t)row * 64 + j] = (unsigned short)f2bf(acc[a]);
  }
}

// Layer-1 aggregation: one wave/node, lane owns cols {2l,2l+1} (uint).
// 4 edges per iteration, guard-free thanks to row padding.
__global__ __launch_bounds__(256) void k_agg128(const int* __restrict__ csrc,
                                                const float* __restrict__ cnrm,
                                                const int* __restrict__ rowptr,
                                                const int* __restrict__ cnt,
                                                const float* __restrict__ dinv,
                                                const float* __restrict__ bias,
                                                const unsigned* __restrict__ xwb,
                                                unsigned* __restrict__ hb, int n) {
  int wid  = (blockIdx.x * blockDim.x + threadIdx.x) >> 6;
  int lane = threadIdx.x & 63;
  if (wid >= n) return;
  int beg = rowptr[wid];
  int ng  = (cnt[wid] + 3) >> 2;
  float di = dinv[wid];
  float sl = di * di;
  unsigned us = xwb[(size_t)wid * 64 + lane];
  float ax = bias[2 * lane]     + bflo(us) * sl;
  float ay = bias[2 * lane + 1] + bfhi(us) * sl;
  float bx = 0.0f, by = 0.0f;
  for (int g = 0; g < ng; ++g) {
    int base = beg + (g << 2);
    int4   s4 = *(const int4*)(csrc + base);
    float4 n4 = *(const float4*)(cnrm + base);
    unsigned u0 = xwb[(size_t)s4.x * 64 + lane];
    unsigned u1 = xwb[(size_t)s4.y * 64 + lane];
    unsigned u2 = xwb[(size_t)s4.z * 64 + lane];
    unsigned u3 = xwb[(size_t)s4.w * 64 + lane];
    ax += bflo(u0) * n4.x; ay += bfhi(u0) * n4.x;
    bx += bflo(u1) * n4.y; by += bfhi(u1) * n4.y;
    ax += bflo(u2) * n4.z; ay += bfhi(u2) * n4.z;
    bx += bflo(u3) * n4.w; by += bfhi(u3) * n4.w;
  }
  float ox = fmaxf(ax + bx, 0.0f), oy = fmaxf(ay + by, 0.0f);
  hb[(size_t)wid * 64 + lane] = f2bf(ox) | (f2bf(oy) << 16);
}

// Layer-2 aggregation + log_softmax. One wave/node; half-wave per edge:
// lanes 0-31 take edges {base,base+1}, lanes 32-63 take {base+2,base+3};
// lane owns cols {2c,2c+1} (c=lane&31) of the bf16 table (uint load).
__global__ __launch_bounds__(256) void k_agg64ls(const int* __restrict__ csrc,
                                                 const float* __restrict__ cnrm,
                                                 const int* __restrict__ rowptr,
                                                 const int* __restrict__ cnt,
                                                 const float* __restrict__ dinv,
                                                 const float* __restrict__ bias,
                                                 const unsigned* __restrict__ hwb,
                                                 float* __restrict__ out, int n) {
  int wid  = (blockIdx.x * blockDim.x + threadIdx.x) >> 6;
  int lane = threadIdx.x & 63;
  if (wid >= n) return;
  int c    = lane & 31;
  int half = lane >> 5;
  int beg = rowptr[wid];
  int ng  = (cnt[wid] + 3) >> 2;
  float ax = 0.0f, ay = 0.0f, bx = 0.0f, by = 0.0f;
  if (half == 0) {   // self-loop + bias counted once
    float di = dinv[wid];
    unsigned us = hwb[(size_t)wid * 32 + c];
    ax = bias[2 * c]     + bflo(us) * di * di;
    ay = bias[2 * c + 1] + bfhi(us) * di * di;
  }
  for (int g = 0; g < ng; ++g) {
    int base = beg + (g << 2);
    int4   s4 = *(const int4*)(csrc + base);
    float4 n4 = *(const float4*)(cnrm + base);
    int   sA = half ? s4.z : s4.x;
    int   sB = half ? s4.w : s4.y;
    float nA = half ? n4.z : n4.x;
    float nB = half ? n4.w : n4.y;
    unsigned uA = hwb[(size_t)sA * 32 + c];
    unsigned uB = hwb[(size_t)sB * 32 + c];
    ax += bflo(uA) * nA; ay += bfhi(uA) * nA;
    bx += bflo(uB) * nB; by += bfhi(uB) * nB;
  }
  float vx = ax + bx, vy = ay + by;
  vx += __shfl_xor(vx, 32);            // cross-half sum
  vy += __shfl_xor(vy, 32);
  float m = fmaxf(vx, vy);
  for (int o = 16; o > 0; o >>= 1) m = fmaxf(m, __shfl_xor(m, o));
  float s = expf(vx - m) + expf(vy - m);
  for (int o = 16; o > 0; o >>= 1) s += __shfl_xor(s, o);
  float ls = logf(s);
  if (half == 0) {
    float2 o2 = { vx - m - ls, vy - m - ls };
    *(float2*)(out + (size_t)wid * 64 + 2 * c) = o2;
  }
}

extern "C" void kernel_launch(void* const* d_in, const int* in_sizes, int n_in,
                              void* d_out, int out_size, void* d_ws, size_t ws_size,
                              hipStream_t stream) {
  const float* x  = (const float*)d_in[0];
  const int*   ei = (const int*)d_in[1];
  const float* W1 = (const float*)d_in[2];
  const float* b1 = (const float*)d_in[3];
  const float* W2 = (const float*)d_in[4];
  const float* b2 = (const float*)d_in[5];
  float* out = (float*)d_out;

  const int n = in_sizes[0] / N_FEAT;   // 50000
  const int E = in_sizes[1] / 2;        // 800000
  const int* src = ei;
  const int* dst = ei + E;
  const int nb = (n + 255) / 256;       // 196

  auto align = [](size_t v) { return (v + 255) & ~(size_t)255; };
  char* ws = (char*)d_ws;
  size_t off = 0;
  int*      cnt    = (int*)     (ws + off); off += align((size_t)n * 4);
  int*      rowptr = (int*)     (ws + off); off += align((size_t)n * 4);
  float*    dinv   = (float*)   (ws + off); off += align((size_t)n * 4);
  int*      rank   = (int*)     (ws + off); off += align((size_t)E * 4);
  int*      bsum   = (int*)     (ws + off); off += align(256 * 4);
  int*      bbase  = (int*)     (ws + off); off += align(256 * 4);
  int*      csrc   = (int*)     (ws + off); off += align((size_t)(E + 4 * n) * 4);
  float*    cnrm   = (float*)   (ws + off); off += align((size_t)(E + 4 * n) * 4);
  unsigned* xwb    = (unsigned*)(ws + off); off += align((size_t)n * 64 * 4);  // bf16[n,128]
  unsigned* hb     = (unsigned*)(ws + off); off += align((size_t)n * 64 * 4);  // bf16[n,128]
  unsigned* hwb    = xwb;  // bf16[n,64] overlays xwb (dead after agg128)

  hipMemsetAsync(cnt, 0, (size_t)n * 4, stream);
  k_hist<<<(E + 255) / 256, 256, 0, stream>>>(dst, cnt, rank, E);
  k_bsum<<<nb, 256, 0, stream>>>(cnt, bsum, n);
  k_bscan<<<1, 256, 0, stream>>>(bsum, bbase, nb);
  k_scan2<<<nb, 256, 0, stream>>>(cnt, bbase, rowptr, dinv, n);
  k_pad<<<nb, 256, 0, stream>>>(rowptr, cnt, csrc, cnrm, n);
  k_fill<<<(E + 255) / 256, 256, 0, stream>>>(src, dst, rank, rowptr, dinv, csrc, cnrm, E);

  // Layer 1
  k_gemm1<<<(n + 15) / 16, 256, 0, stream>>>(x, W1, (unsigned short*)xwb, n);
  k_agg128<<<(int)(((size_t)n * 64 + 255) / 256), 256, 0, stream>>>(
      csrc, cnrm, rowptr, cnt, dinv, b1, xwb, hb, n);

  // Layer 2
  k_gemm2<<<(n + 15) / 16, 256, 0, stream>>>(hb, W2, (unsigned short*)hwb, n);
  k_agg64ls<<<(int)(((size_t)n * 64 + 255) / 256), 256, 0, stream>>>(
      csrc, cnrm, rowptr, cnt, dinv, b2, hwb, out, n);
}

// Round 5
// 259.997 us; speedup vs baseline: 8.6401x; 1.0762x over previous
//
#include <hip/hip_runtime.h>
#include <cstdint>
#include <cstddef>

// GCN on MI355X, round 5.
//   out[50000,64] = log_softmax(gcn2(relu(gcn1(x))))
// New this round:
//  - packed 4B edge descriptors: (bf16 nrm << 16) | src  (src < 65536)
//  - edge-balanced multi-row waves (8192 waves, binary-searched row ranges)
//  - k_pad folded into k_scan2
// CSR rows padded to multiples of 4 edges (desc=0 dummies: src=0, nrm=0).

#define N_FEAT 128
#define NWAVE 8192   // 2048 blocks x 4 waves = full 32-wave/CU residency

__device__ __forceinline__ unsigned f2bf(float f) {
  unsigned u = __float_as_uint(f);
  return (u + 0x7FFFu + ((u >> 16) & 1u)) >> 16;   // round-to-nearest-even
}
__device__ __forceinline__ float bflo(unsigned u) { return __uint_as_float(u << 16); }
__device__ __forceinline__ float bfhi(unsigned u) { return __uint_as_float(u & 0xFFFF0000u); }

// Histogram of dst + per-edge within-row rank (makes fill atomic-free).
__global__ void k_hist(const int* __restrict__ dst, int* __restrict__ cnt,
                       int* __restrict__ rank, int E) {
  int e = blockIdx.x * blockDim.x + threadIdx.x;
  if (e < E) rank[e] = atomicAdd(&cnt[dst[e]], 1);
}

// Per-block sums of PADDED counts (pad each row to multiple of 4).
__global__ __launch_bounds__(256) void k_bsum(const int* __restrict__ cnt,
                                              int* __restrict__ bsum, int n) {
  int i = blockIdx.x * 256 + threadIdx.x;
  int v = (i < n) ? ((cnt[i] + 3) & ~3) : 0;
  for (int o = 32; o > 0; o >>= 1) v += __shfl_down(v, o);
  __shared__ int w[4];
  if ((threadIdx.x & 63) == 0) w[threadIdx.x >> 6] = v;
  __syncthreads();
  if (threadIdx.x == 0) bsum[blockIdx.x] = w[0] + w[1] + w[2] + w[3];
}

__global__ __launch_bounds__(256) void k_bscan(const int* __restrict__ bsum,
                                               int* __restrict__ bbase, int nb) {
  __shared__ int lds[256];
  int t = threadIdx.x;
  int v = (t < nb) ? bsum[t] : 0;
  lds[t] = v;
  __syncthreads();
  for (int o = 1; o < 256; o <<= 1) {
    int u = (t >= o) ? lds[t - o] : 0;
    __syncthreads();
    lds[t] += u;
    __syncthreads();
  }
  if (t < nb) bbase[t] = lds[t] - v;   // exclusive
}

// Local scan -> rowptr (padded), dinv, and zero the pad descriptor slots.
__global__ __launch_bounds__(256) void k_scan2(const int* __restrict__ cnt,
                                               const int* __restrict__ bbase,
                                               int* __restrict__ rowptr,
                                               float* __restrict__ dinv,
                                               unsigned* __restrict__ desc, int n) {
  __shared__ int lds[256];
  int t = threadIdx.x;
  int i = blockIdx.x * 256 + t;
  int c  = (i < n) ? cnt[i] : 0;
  int pc = (c + 3) & ~3;
  lds[t] = pc;
  __syncthreads();
  for (int o = 1; o < 256; o <<= 1) {
    int u = (t >= o) ? lds[t - o] : 0;
    __syncthreads();
    lds[t] += u;
    __syncthreads();
  }
  if (i < n) {
    int excl = bbase[blockIdx.x] + lds[t] - pc;
    rowptr[i] = excl;
    dinv[i] = rsqrtf((float)(c + 1));          // +1 self-loop
    for (int p = excl + c; p < excl + pc; ++p) desc[p] = 0;  // dummy edges
    if (i == n - 1) rowptr[n] = excl + pc;
  }
}

// Per-wave start row: first r with rowptr[r] >= w*Epad/NWAVE.
__global__ void k_wstart(const int* __restrict__ rowptr, int* __restrict__ wstart, int n) {
  int w = blockIdx.x * blockDim.x + threadIdx.x;
  if (w > NWAVE) return;
  if (w == NWAVE) { wstart[w] = n; return; }
  long long target = (long long)rowptr[n] * w / NWAVE;
  int lo = 0, hi = n;
  while (lo < hi) {
    int mid = (lo + hi) >> 1;
    if (rowptr[mid] < (int)target) lo = mid + 1; else hi = mid;
  }
  wstart[w] = lo;
}

// Atomic-free CSR fill with packed descriptors.
__global__ void k_fill(const int* __restrict__ src, const int* __restrict__ dst,
                       const int* __restrict__ rank, const int* __restrict__ rowptr,
                       const float* __restrict__ dinv,
                       unsigned* __restrict__ desc, int E) {
  int e = blockIdx.x * blockDim.x + threadIdx.x;
  if (e >= E) return;
  int s = src[e], d = dst[e];
  int p = rowptr[d] + rank[e];
  desc[p] = (f2bf(dinv[s] * dinv[d]) << 16) | (unsigned)s;
}

// GEMM1: Yb[n,128](bf16) = X[n,128](f32) @ W[128,128].
__global__ __launch_bounds__(256) void k_gemm1(const float* __restrict__ X,
                                               const float* __restrict__ W,
                                               unsigned short* __restrict__ Yb, int n) {
  __shared__ float XlT[128][20];
  int row0 = blockIdx.x * 16;
  for (int it = 0; it < 8; ++it) {
    int idx = threadIdx.x + it * 256;
    int r = idx >> 7, k = idx & 127;
    int row = row0 + r;
    XlT[k][r] = (row < n) ? X[(size_t)row * 128 + k] : 0.0f;
  }
  __syncthreads();
  int j  = threadIdx.x & 127;
  int rs = (threadIdx.x >> 7) * 8;
  float acc[8];
#pragma unroll
  for (int a = 0; a < 8; ++a) acc[a] = 0.0f;
#pragma unroll 4
  for (int k = 0; k < 128; ++k) {
    float w = W[k * 128 + j];
    float4 a0 = *(const float4*)&XlT[k][rs];
    float4 a1 = *(const float4*)&XlT[k][rs + 4];
    acc[0] += a0.x * w; acc[1] += a0.y * w; acc[2] += a0.z * w; acc[3] += a0.w * w;
    acc[4] += a1.x * w; acc[5] += a1.y * w; acc[6] += a1.z * w; acc[7] += a1.w * w;
  }
#pragma unroll
  for (int a = 0; a < 8; ++a) {
    int row = row0 + rs + a;
    if (row < n) Yb[(size_t)row * 128 + j] = (unsigned short)f2bf(acc[a]);
  }
}

// GEMM2: hwb[n,64](bf16) = Hb[n,128](bf16) @ W2[128,64].
__global__ __launch_bounds__(256) void k_gemm2(const unsigned* __restrict__ Hu,
                                               const float* __restrict__ W,
                                               unsigned short* __restrict__ Yb, int n) {
  __shared__ float XlT[128][20];
  int row0 = blockIdx.x * 16;
  for (int it = 0; it < 4; ++it) {
    int idx = threadIdx.x + it * 256;
    int r = idx >> 6, k2 = idx & 63;
    int row = row0 + r;
    unsigned u = (row < n) ? Hu[(size_t)row * 64 + k2] : 0u;
    XlT[2 * k2][r]     = bflo(u);
    XlT[2 * k2 + 1][r] = bfhi(u);
  }
  __syncthreads();
  int j  = threadIdx.x & 63;
  int rs = (threadIdx.x >> 6) * 4;
  float acc[4];
#pragma unroll
  for (int a = 0; a < 4; ++a) acc[a] = 0.0f;
#pragma unroll 4
  for (int k = 0; k < 128; ++k) {
    float w = W[k * 64 + j];
    float4 a0 = *(const float4*)&XlT[k][rs];
    acc[0] += a0.x * w; acc[1] += a0.y * w; acc[2] += a0.z * w; acc[3] += a0.w * w;
  }
#pragma unroll
  for (int a = 0; a < 4; ++a) {
    int row = row0 + rs + a;
    if (row < n) Yb[(size_t)row * 64 + j] = (unsigned short)f2bf(acc[a]);
  }
}

// Layer-1 aggregation: each wave owns rows [wstart[w], wstart[w+1]).
// Lane owns cols {2l,2l+1} (uint). 4 edges/iter, guard-free (padded rows).
__global__ __launch_bounds__(256) void k_agg128(const unsigned* __restrict__ desc,
                                                const int* __restrict__ rowptr,
                                                const int* __restrict__ wstart,
                                                const float* __restrict__ dinv,
                                                const float* __restrict__ bias,
                                                const unsigned* __restrict__ xwb,
                                                unsigned* __restrict__ hb, int n) {
  int w    = (blockIdx.x * blockDim.x + threadIdx.x) >> 6;
  int lane = threadIdx.x & 63;
  if (w >= NWAVE) return;
  int r0 = wstart[w], r1 = wstart[w + 1];
  if (r0 >= r1) return;
  float bx0 = bias[2 * lane], bx1 = bias[2 * lane + 1];
  int beg = rowptr[r0];
  for (int r = r0; r < r1; ++r) {
    int end = rowptr[r + 1];
    float di = dinv[r];
    float sl = di * di;
    unsigned us = xwb[(size_t)r * 64 + lane];
    float ax = bx0 + bflo(us) * sl;
    float ay = bx1 + bfhi(us) * sl;
    float bx = 0.0f, by = 0.0f;
    for (int base = beg; base < end; base += 4) {
      uint4 d4 = *(const uint4*)(desc + base);
      unsigned u0 = xwb[(size_t)(d4.x & 0xFFFFu) * 64 + lane];
      unsigned u1 = xwb[(size_t)(d4.y & 0xFFFFu) * 64 + lane];
      unsigned u2 = xwb[(size_t)(d4.z & 0xFFFFu) * 64 + lane];
      unsigned u3 = xwb[(size_t)(d4.w & 0xFFFFu) * 64 + lane];
      float n0 = bfhi(d4.x), n1 = bfhi(d4.y), n2 = bfhi(d4.z), n3 = bfhi(d4.w);
      ax += bflo(u0) * n0; ay += bfhi(u0) * n0;
      bx += bflo(u1) * n1; by += bfhi(u1) * n1;
      ax += bflo(u2) * n2; ay += bfhi(u2) * n2;
      bx += bflo(u3) * n3; by += bfhi(u3) * n3;
    }
    float ox = fmaxf(ax + bx, 0.0f), oy = fmaxf(ay + by, 0.0f);
    hb[(size_t)r * 64 + lane] = f2bf(ox) | (f2bf(oy) << 16);
    beg = end;
  }
}

// Layer-2 aggregation + log_softmax, multi-row waves.
// Half-wave per edge-pair: lanes 0-31 edges {0,1} of quad, 32-63 edges {2,3};
// lane owns cols {2c,2c+1} (c=lane&31) of the bf16 table.
__global__ __launch_bounds__(256) void k_agg64ls(const unsigned* __restrict__ desc,
                                                 const int* __restrict__ rowptr,
                                                 const int* __restrict__ wstart,
                                                 const float* __restrict__ dinv,
                                                 const float* __restrict__ bias,
                                                 const unsigned* __restrict__ hwb,
                                                 float* __restrict__ out, int n) {
  int w    = (blockIdx.x * blockDim.x + threadIdx.x) >> 6;
  int lane = threadIdx.x & 63;
  if (w >= NWAVE) return;
  int r0 = wstart[w], r1 = wstart[w + 1];
  if (r0 >= r1) return;
  int c    = lane & 31;
  int half = lane >> 5;
  float bc0 = bias[2 * c], bc1 = bias[2 * c + 1];
  int beg = rowptr[r0];
  for (int r = r0; r < r1; ++r) {
    int end = rowptr[r + 1];
    float ax = 0.0f, ay = 0.0f, bx = 0.0f, by = 0.0f;
    if (half == 0) {   // self-loop + bias counted once
      float di = dinv[r];
      unsigned us = hwb[(size_t)r * 32 + c];
      ax = bc0 + bflo(us) * di * di;
      ay = bc1 + bfhi(us) * di * di;
    }
    for (int base = beg; base < end; base += 4) {
      uint4 d4 = *(const uint4*)(desc + base);
      unsigned dA = half ? d4.z : d4.x;
      unsigned dB = half ? d4.w : d4.y;
      unsigned uA = hwb[(size_t)(dA & 0xFFFFu) * 32 + c];
      unsigned uB = hwb[(size_t)(dB & 0xFFFFu) * 32 + c];
      float nA = bfhi(dA), nB = bfhi(dB);
      ax += bflo(uA) * nA; ay += bfhi(uA) * nA;
      bx += bflo(uB) * nB; by += bfhi(uB) * nB;
    }
    float vx = ax + bx, vy = ay + by;
    vx += __shfl_xor(vx, 32);          // cross-half sum
    vy += __shfl_xor(vy, 32);
    float m = fmaxf(vx, vy);
    for (int o = 16; o > 0; o >>= 1) m = fmaxf(m, __shfl_xor(m, o));
    float s = expf(vx - m) + expf(vy - m);
    for (int o = 16; o > 0; o >>= 1) s += __shfl_xor(s, o);
    float ls = logf(s);
    if (half == 0) {
      float2 o2 = { vx - m - ls, vy - m - ls };
      *(float2*)(out + (size_t)r * 64 + 2 * c) = o2;
    }
    beg = end;
  }
}

extern "C" void kernel_launch(void* const* d_in, const int* in_sizes, int n_in,
                              void* d_out, int out_size, void* d_ws, size_t ws_size,
                              hipStream_t stream) {
  const float* x  = (const float*)d_in[0];
  const int*   ei = (const int*)d_in[1];
  const float* W1 = (const float*)d_in[2];
  const float* b1 = (const float*)d_in[3];
  const float* W2 = (const float*)d_in[4];
  const float* b2 = (const float*)d_in[5];
  float* out = (float*)d_out;

  const int n = in_sizes[0] / N_FEAT;   // 50000
  const int E = in_sizes[1] / 2;        // 800000
  const int* src = ei;
  const int* dst = ei + E;
  const int nb = (n + 255) / 256;       // 196

  auto align = [](size_t v) { return (v + 255) & ~(size_t)255; };
  char* ws = (char*)d_ws;
  size_t off = 0;
  int*      cnt    = (int*)     (ws + off); off += align((size_t)n * 4);
  int*      rowptr = (int*)     (ws + off); off += align((size_t)(n + 1) * 4);
  float*    dinv   = (float*)   (ws + off); off += align((size_t)n * 4);
  int*      rank   = (int*)     (ws + off); off += align((size_t)E * 4);
  int*      bsum   = (int*)     (ws + off); off += align(256 * 4);
  int*      bbase  = (int*)     (ws + off); off += align(256 * 4);
  int*      wstart = (int*)     (ws + off); off += align((size_t)(NWAVE + 1) * 4);
  unsigned* desc   = (unsigned*)(ws + off); off += align((size_t)(E + 4 * n) * 4);
  unsigned* xwb    = (unsigned*)(ws + off); off += align((size_t)n * 64 * 4);  // bf16[n,128]
  unsigned* hb     = (unsigned*)(ws + off); off += align((size_t)n * 64 * 4);  // bf16[n,128]
  unsigned* hwb    = xwb;  // bf16[n,64] overlays xwb (dead after agg128)

  hipMemsetAsync(cnt, 0, (size_t)n * 4, stream);
  k_hist<<<(E + 255) / 256, 256, 0, stream>>>(dst, cnt, rank, E);
  k_bsum<<<nb, 256, 0, stream>>>(cnt, bsum, n);
  k_bscan<<<1, 256, 0, stream>>>(bsum, bbase, nb);
  k_scan2<<<nb, 256, 0, stream>>>(cnt, bbase, rowptr, dinv, desc, n);
  k_wstart<<<(NWAVE + 256) / 256, 256, 0, stream>>>(rowptr, wstart, n);
  k_fill<<<(E + 255) / 256, 256, 0, stream>>>(src, dst, rank, rowptr, dinv, desc, E);

  // Layer 1
  k_gemm1<<<(n + 15) / 16, 256, 0, stream>>>(x, W1, (unsigned short*)xwb, n);
  k_agg128<<<NWAVE / 4, 256, 0, stream>>>(desc, rowptr, wstart, dinv, b1, xwb, hb, n);

  // Layer 2
  k_gemm2<<<(n + 15) / 16, 256, 0, stream>>>(hb, W2, (unsigned short*)hwb, n);
  k_agg64ls<<<NWAVE / 4, 256, 0, stream>>>(desc, rowptr, wstart, dinv, b2, hwb, out, n);
}

// Round 6
// 231.193 us; speedup vs baseline: 9.7166x; 1.1246x over previous
//
#include <hip/hip_runtime.h>
#include <cstdint>
#include <cstddef>

// GCN on MI355X, round 6: MFMA bf16 GEMMs.
//   out[50000,64] = log_softmax(gcn2(relu(gcn1(x))))
// Pipeline: hist(+rank) -> 2-level padded scan(+pad) -> wstart -> fill ->
//   MFMA-GEMM1(f32->bf16) -> agg128 -> MFMA-GEMM2(bf16->bf16) -> agg64+ls
// GEMMs: 64 rows/block, 4 waves; mfma_f32_16x16x32_bf16; X and W^T staged in
// LDS as 16B chunks with chunk^=(row&7) XOR swizzle (<=2-way bank conflicts).

#define N_FEAT 128
#define NWAVE 8192   // 2048 blocks x 4 waves = full residency

typedef short bf16x8 __attribute__((ext_vector_type(8)));
typedef float f32x4 __attribute__((ext_vector_type(4)));

__device__ __forceinline__ unsigned f2bf(float f) {
  unsigned u = __float_as_uint(f);
  return (u + 0x7FFFu + ((u >> 16) & 1u)) >> 16;   // round-to-nearest-even
}
__device__ __forceinline__ float bflo(unsigned u) { return __uint_as_float(u << 16); }
__device__ __forceinline__ float bfhi(unsigned u) { return __uint_as_float(u & 0xFFFF0000u); }

// ---------------- preprocessing ----------------

__global__ void k_hist(const int* __restrict__ dst, int* __restrict__ cnt,
                       int* __restrict__ rank, int E) {
  int e = blockIdx.x * blockDim.x + threadIdx.x;
  if (e < E) rank[e] = atomicAdd(&cnt[dst[e]], 1);
}

__global__ __launch_bounds__(256) void k_bsum(const int* __restrict__ cnt,
                                              int* __restrict__ bsum, int n) {
  int i = blockIdx.x * 256 + threadIdx.x;
  int v = (i < n) ? ((cnt[i] + 3) & ~3) : 0;
  for (int o = 32; o > 0; o >>= 1) v += __shfl_down(v, o);
  __shared__ int w[4];
  if ((threadIdx.x & 63) == 0) w[threadIdx.x >> 6] = v;
  __syncthreads();
  if (threadIdx.x == 0) bsum[blockIdx.x] = w[0] + w[1] + w[2] + w[3];
}

__global__ __launch_bounds__(256) void k_bscan(const int* __restrict__ bsum,
                                               int* __restrict__ bbase, int nb) {
  __shared__ int lds[256];
  int t = threadIdx.x;
  int v = (t < nb) ? bsum[t] : 0;
  lds[t] = v;
  __syncthreads();
  for (int o = 1; o < 256; o <<= 1) {
    int u = (t >= o) ? lds[t - o] : 0;
    __syncthreads();
    lds[t] += u;
    __syncthreads();
  }
  if (t < nb) bbase[t] = lds[t] - v;   // exclusive
}

__global__ __launch_bounds__(256) void k_scan2(const int* __restrict__ cnt,
                                               const int* __restrict__ bbase,
                                               int* __restrict__ rowptr,
                                               float* __restrict__ dinv,
                                               unsigned* __restrict__ desc, int n) {
  __shared__ int lds[256];
  int t = threadIdx.x;
  int i = blockIdx.x * 256 + t;
  int c  = (i < n) ? cnt[i] : 0;
  int pc = (c + 3) & ~3;
  lds[t] = pc;
  __syncthreads();
  for (int o = 1; o < 256; o <<= 1) {
    int u = (t >= o) ? lds[t - o] : 0;
    __syncthreads();
    lds[t] += u;
    __syncthreads();
  }
  if (i < n) {
    int excl = bbase[blockIdx.x] + lds[t] - pc;
    rowptr[i] = excl;
    dinv[i] = rsqrtf((float)(c + 1));          // +1 self-loop
    for (int p = excl + c; p < excl + pc; ++p) desc[p] = 0;  // dummy edges
    if (i == n - 1) rowptr[n] = excl + pc;
  }
}

__global__ void k_wstart(const int* __restrict__ rowptr, int* __restrict__ wstart, int n) {
  int w = blockIdx.x * blockDim.x + threadIdx.x;
  if (w > NWAVE) return;
  if (w == NWAVE) { wstart[w] = n; return; }
  long long target = (long long)rowptr[n] * w / NWAVE;
  int lo = 0, hi = n;
  while (lo < hi) {
    int mid = (lo + hi) >> 1;
    if (rowptr[mid] < (int)target) lo = mid + 1; else hi = mid;
  }
  wstart[w] = lo;
}

__global__ void k_fill(const int* __restrict__ src, const int* __restrict__ dst,
                       const int* __restrict__ rank, const int* __restrict__ rowptr,
                       const float* __restrict__ dinv,
                       unsigned* __restrict__ desc, int E) {
  int e = blockIdx.x * blockDim.x + threadIdx.x;
  if (e >= E) return;
  int s = src[e], d = dst[e];
  int p = rowptr[d] + rank[e];
  desc[p] = (f2bf(dinv[s] * dinv[d]) << 16) | (unsigned)s;
}

// ---------------- MFMA GEMMs ----------------
// Y[n,NCOL](bf16) = X[n,128] @ W[128,NCOL].  XF32: X is f32, else packed bf16.
// 64 rows/block (wave w owns rows w*16..w*16+15), full K=128 staged at once.
// Fragment layouts (gfx950, doc-verified):
//   A: row = lane&15, k = (lane>>4)*8 + e (8 consecutive k per lane)
//   B: col = lane&15, k likewise;  D: col = lane&15, row = (lane>>4)*4 + reg.
template<int NCOL, bool XF32>
__global__ __launch_bounds__(256) void k_gemm_mfma(const void* __restrict__ Xv,
                                                   const float* __restrict__ W,
                                                   unsigned short* __restrict__ Yb,
                                                   int n) {
  constexpr int NT = NCOL / 16;          // output column tiles per wave
  __shared__ uint4 Xl[64][16];           // [row][chunk]: 8 bf16 per chunk
  __shared__ uint4 Wl[NCOL][16];         // [col][chunk]
  int t = threadIdx.x;
  int row0 = blockIdx.x * 64;

  // Stage X (1024 chunks), coalesced; chunk index XOR-swizzled by row&7.
  for (int c = t; c < 1024; c += 256) {
    int lr = c >> 4, kc = c & 15;
    int row = row0 + lr;
    uint4 v = {0u, 0u, 0u, 0u};
    if (row < n) {
      if constexpr (XF32) {
        const float* Xf = (const float*)Xv;
        float4 f0 = *(const float4*)(Xf + (size_t)row * 128 + kc * 8);
        float4 f1 = *(const float4*)(Xf + (size_t)row * 128 + kc * 8 + 4);
        v.x = f2bf(f0.x) | (f2bf(f0.y) << 16);
        v.y = f2bf(f0.z) | (f2bf(f0.w) << 16);
        v.z = f2bf(f1.x) | (f2bf(f1.y) << 16);
        v.w = f2bf(f1.z) | (f2bf(f1.w) << 16);
      } else {
        v = ((const uint4*)Xv)[(size_t)row * 16 + kc];
      }
    }
    Xl[lr][kc ^ (lr & 7)] = v;
  }
  // Stage W transposed (NCOL*16 chunks): thread reads 8 strided-by-NCOL f32
  // of column j (coalesced across adjacent threads), packs to bf16.
  {
    int j = t % NCOL, kc0 = t / NCOL;
    for (int kc = kc0; kc < 16; kc += 256 / NCOL) {
      const float* wp = W + (size_t)(kc * 8) * NCOL + j;
      float f[8];
#pragma unroll
      for (int e = 0; e < 8; ++e) f[e] = wp[e * NCOL];
      uint4 v;
      v.x = f2bf(f[0]) | (f2bf(f[1]) << 16);
      v.y = f2bf(f[2]) | (f2bf(f[3]) << 16);
      v.z = f2bf(f[4]) | (f2bf(f[5]) << 16);
      v.w = f2bf(f[6]) | (f2bf(f[7]) << 16);
      Wl[j][kc ^ (j & 7)] = v;
    }
  }
  __syncthreads();

  int w = t >> 6, lane = t & 63;
  int lr16 = lane & 15, kg = lane >> 4;
  bf16x8 a[4];
#pragma unroll
  for (int kk = 0; kk < 4; ++kk)
    a[kk] = __builtin_bit_cast(bf16x8, Xl[w * 16 + lr16][(kk * 4 + kg) ^ (lane & 7)]);
#pragma unroll
  for (int jt = 0; jt < NT; ++jt) {
    f32x4 acc = {0.0f, 0.0f, 0.0f, 0.0f};
#pragma unroll
    for (int kk = 0; kk < 4; ++kk) {
      bf16x8 b = __builtin_bit_cast(bf16x8, Wl[jt * 16 + lr16][(kk * 4 + kg) ^ (lane & 7)]);
      acc = __builtin_amdgcn_mfma_f32_16x16x32_bf16(a[kk], b, acc, 0, 0, 0);
    }
    int col = jt * 16 + lr16;
#pragma unroll
    for (int r = 0; r < 4; ++r) {
      int row = row0 + w * 16 + kg * 4 + r;
      if (row < n) Yb[(size_t)row * NCOL + col] = (unsigned short)f2bf(acc[r]);
    }
  }
}

// ---------------- aggregations ----------------

// Layer-1: each wave owns rows [wstart[w], wstart[w+1]); lane owns cols {2l,2l+1}.
__global__ __launch_bounds__(256) void k_agg128(const unsigned* __restrict__ desc,
                                                const int* __restrict__ rowptr,
                                                const int* __restrict__ wstart,
                                                const float* __restrict__ dinv,
                                                const float* __restrict__ bias,
                                                const unsigned* __restrict__ xwb,
                                                unsigned* __restrict__ hb, int n) {
  int w    = (blockIdx.x * blockDim.x + threadIdx.x) >> 6;
  int lane = threadIdx.x & 63;
  if (w >= NWAVE) return;
  int r0 = wstart[w], r1 = wstart[w + 1];
  if (r0 >= r1) return;
  float bx0 = bias[2 * lane], bx1 = bias[2 * lane + 1];
  int beg = rowptr[r0];
  for (int r = r0; r < r1; ++r) {
    int end = rowptr[r + 1];
    float di = dinv[r];
    float sl = di * di;
    unsigned us = xwb[(size_t)r * 64 + lane];
    float ax = bx0 + bflo(us) * sl;
    float ay = bx1 + bfhi(us) * sl;
    float bx = 0.0f, by = 0.0f;
    for (int base = beg; base < end; base += 4) {
      uint4 d4 = *(const uint4*)(desc + base);
      unsigned u0 = xwb[(size_t)(d4.x & 0xFFFFu) * 64 + lane];
      unsigned u1 = xwb[(size_t)(d4.y & 0xFFFFu) * 64 + lane];
      unsigned u2 = xwb[(size_t)(d4.z & 0xFFFFu) * 64 + lane];
      unsigned u3 = xwb[(size_t)(d4.w & 0xFFFFu) * 64 + lane];
      float n0 = bfhi(d4.x), n1 = bfhi(d4.y), n2 = bfhi(d4.z), n3 = bfhi(d4.w);
      ax += bflo(u0) * n0; ay += bfhi(u0) * n0;
      bx += bflo(u1) * n1; by += bfhi(u1) * n1;
      ax += bflo(u2) * n2; ay += bfhi(u2) * n2;
      bx += bflo(u3) * n3; by += bfhi(u3) * n3;
    }
    float ox = fmaxf(ax + bx, 0.0f), oy = fmaxf(ay + by, 0.0f);
    hb[(size_t)r * 64 + lane] = f2bf(ox) | (f2bf(oy) << 16);
    beg = end;
  }
}

// Layer-2 + log_softmax: half-wave per edge-pair; lane owns cols {2c,2c+1}.
__global__ __launch_bounds__(256) void k_agg64ls(const unsigned* __restrict__ desc,
                                                 const int* __restrict__ rowptr,
                                                 const int* __restrict__ wstart,
                                                 const float* __restrict__ dinv,
                                                 const float* __restrict__ bias,
                                                 const unsigned* __restrict__ hwb,
                                                 float* __restrict__ out, int n) {
  int w    = (blockIdx.x * blockDim.x + threadIdx.x) >> 6;
  int lane = threadIdx.x & 63;
  if (w >= NWAVE) return;
  int r0 = wstart[w], r1 = wstart[w + 1];
  if (r0 >= r1) return;
  int c    = lane & 31;
  int half = lane >> 5;
  float bc0 = bias[2 * c], bc1 = bias[2 * c + 1];
  int beg = rowptr[r0];
  for (int r = r0; r < r1; ++r) {
    int end = rowptr[r + 1];
    float ax = 0.0f, ay = 0.0f, bx = 0.0f, by = 0.0f;
    if (half == 0) {   // self-loop + bias counted once
      float di = dinv[r];
      unsigned us = hwb[(size_t)r * 32 + c];
      ax = bc0 + bflo(us) * di * di;
      ay = bc1 + bfhi(us) * di * di;
    }
    for (int base = beg; base < end; base += 4) {
      uint4 d4 = *(const uint4*)(desc + base);
      unsigned dA = half ? d4.z : d4.x;
      unsigned dB = half ? d4.w : d4.y;
      unsigned uA = hwb[(size_t)(dA & 0xFFFFu) * 32 + c];
      unsigned uB = hwb[(size_t)(dB & 0xFFFFu) * 32 + c];
      float nA = bfhi(dA), nB = bfhi(dB);
      ax += bflo(uA) * nA; ay += bfhi(uA) * nA;
      bx += bflo(uB) * nB; by += bfhi(uB) * nB;
    }
    float vx = ax + bx, vy = ay + by;
    vx += __shfl_xor(vx, 32);
    vy += __shfl_xor(vy, 32);
    float m = fmaxf(vx, vy);
    for (int o = 16; o > 0; o >>= 1) m = fmaxf(m, __shfl_xor(m, o));
    float s = expf(vx - m) + expf(vy - m);
    for (int o = 16; o > 0; o >>= 1) s += __shfl_xor(s, o);
    float ls = logf(s);
    if (half == 0) {
      float2 o2 = { vx - m - ls, vy - m - ls };
      *(float2*)(out + (size_t)r * 64 + 2 * c) = o2;
    }
    beg = end;
  }
}

extern "C" void kernel_launch(void* const* d_in, const int* in_sizes, int n_in,
                              void* d_out, int out_size, void* d_ws, size_t ws_size,
                              hipStream_t stream) {
  const float* x  = (const float*)d_in[0];
  const int*   ei = (const int*)d_in[1];
  const float* W1 = (const float*)d_in[2];
  const float* b1 = (const float*)d_in[3];
  const float* W2 = (const float*)d_in[4];
  const float* b2 = (const float*)d_in[5];
  float* out = (float*)d_out;

  const int n = in_sizes[0] / N_FEAT;   // 50000
  const int E = in_sizes[1] / 2;        // 800000
  const int* src = ei;
  const int* dst = ei + E;
  const int nb = (n + 255) / 256;       // 196

  auto align = [](size_t v) { return (v + 255) & ~(size_t)255; };
  char* ws = (char*)d_ws;
  size_t off = 0;
  int*      cnt    = (int*)     (ws + off); off += align((size_t)n * 4);
  int*      rowptr = (int*)     (ws + off); off += align((size_t)(n + 1) * 4);
  float*    dinv   = (float*)   (ws + off); off += align((size_t)n * 4);
  int*      rank   = (int*)     (ws + off); off += align((size_t)E * 4);
  int*      bsum   = (int*)     (ws + off); off += align(256 * 4);
  int*      bbase  = (int*)     (ws + off); off += align(256 * 4);
  int*      wstart = (int*)     (ws + off); off += align((size_t)(NWAVE + 1) * 4);
  unsigned* desc   = (unsigned*)(ws + off); off += align((size_t)(E + 4 * n) * 4);
  unsigned* xwb    = (unsigned*)(ws + off); off += align((size_t)n * 64 * 4);  // bf16[n,128]
  unsigned* hb     = (unsigned*)(ws + off); off += align((size_t)n * 64 * 4);  // bf16[n,128]
  unsigned* hwb    = xwb;  // bf16[n,64] overlays xwb (dead after agg128)

  hipMemsetAsync(cnt, 0, (size_t)n * 4, stream);
  k_hist<<<(E + 255) / 256, 256, 0, stream>>>(dst, cnt, rank, E);
  k_bsum<<<nb, 256, 0, stream>>>(cnt, bsum, n);
  k_bscan<<<1, 256, 0, stream>>>(bsum, bbase, nb);
  k_scan2<<<nb, 256, 0, stream>>>(cnt, bbase, rowptr, dinv, desc, n);
  k_wstart<<<(NWAVE + 256) / 256, 256, 0, stream>>>(rowptr, wstart, n);
  k_fill<<<(E + 255) / 256, 256, 0, stream>>>(src, dst, rank, rowptr, dinv, desc, E);

  // Layer 1
  k_gemm_mfma<128, true><<<(n + 63) / 64, 256, 0, stream>>>(
      x, W1, (unsigned short*)xwb, n);
  k_agg128<<<NWAVE / 4, 256, 0, stream>>>(desc, rowptr, wstart, dinv, b1, xwb, hb, n);

  // Layer 2
  k_gemm_mfma<64, false><<<(n + 63) / 64, 256, 0, stream>>>(
      hb, W2, (unsigned short*)hwb, n);
  k_agg64ls<<<NWAVE / 4, 256, 0, stream>>>(desc, rowptr, wstart, dinv, b2, hwb, out, n);
}